// Round 7
// baseline (335.382 us; speedup 1.0000x reference)
//
#include <hip/hip_runtime.h>

// Problem constants (B=8, C=512, H=W=64, K=19 classes)
#define NCLS   19
#define NB     8
#define NC     512
#define NHW    4096      // 64*64
#define EPSM   1e-6f     // mean denominator eps
#define EPSC   1e-8f     // cosine eps

// Workspace layout (bytes)
#define OFF_LABELS   0u          // int32 [NB*NHW]
#define OFF_COUNTS   131072u     // float [NB*NCLS]
#define OFF_SUMS_S   132096u     // float [NB][NCLS][NC] (becomes means in place)
#define OFF_SUMS_T   443392u
#define OFF_NORM_S   754688u
#define OFF_NORM_T   755712u
#define OFF_PART     756736u     // float [4 arrays][8 chunks][NB*NHW] = 4 MB
// total ~4.95 MB

// ---------------------------------------------------------------------------
// Wave-64 sum via DPP. Result valid in lane 63. (Only used in tiny kernels —
// r6 measured: DPP chains are too expensive for the hot segmented-sum path.)
template<int CTRL>
__device__ __forceinline__ float dpp_add(float x) {
    int y = __builtin_amdgcn_update_dpp(0, __float_as_int(x), CTRL, 0xf, 0xf, false);
    return x + __int_as_float(y);
}
__device__ __forceinline__ float wave64_sum(float x) {
    x = dpp_add<0x111>(x);   // row_shr:1
    x = dpp_add<0x112>(x);   // row_shr:2
    x = dpp_add<0x114>(x);   // row_shr:4
    x = dpp_add<0x118>(x);   // row_shr:8
    x = dpp_add<0x142>(x);   // row_bcast:15
    x = dpp_add<0x143>(x);   // row_bcast:31 -> lane63 has total
    return x;
}

// ---------------------------------------------------------------------------
// Kernel 1: nearest-resize labels + per-batch class counts (one block per
// batch -> counts written directly, no atomics/memset). Also zeroes d_out.
__global__ __launch_bounds__(256) void k_labels(const int* __restrict__ target,
                                                int* __restrict__ labels,
                                                float* __restrict__ counts,
                                                float* __restrict__ out) {
    __shared__ int hist[NCLS];
    const int b = blockIdx.x;
    const int t = threadIdx.x;
    if (b == 0 && t == 0) out[0] = 0.f;   // stream-ordered before k_final
    if (t < NCLS) hist[t] = 0;
    __syncthreads();
    const int* tb = target + (size_t)b * 512 * 512;
    #pragma unroll
    for (int i = 0; i < 16; ++i) {
        int n = t + i * 256;
        int y = n >> 6, x = n & 63;
        int l = tb[(y * 8) * 512 + x * 8];   // in_idx = floor(out_idx*512/64)
        labels[b * NHW + n] = l;
        if (l >= 0 && l < NCLS) atomicAdd(&hist[l], 1);
    }
    __syncthreads();
    if (t < NCLS) counts[b * NCLS + t] = (float)hist[t];
}

// ---------------------------------------------------------------------------
// Kernel 2: per-class channel sums via LDS float atomics (ds_add_f32).
// Each wave owns ONE channel of BOTH tensors, all 4096 pixels.
// Per-wave LDS accumulators: [row S/T][copy = lane>>4][33 slots]; copy
// stride 33 -> class l, copy p lands in bank (l+p)%32: same class in
// different copies never bank-collides; same-address atomic multiplicity
// within a 16-lane copy ~2-3. Slot 19 = dummy for clamped labels.
// r4-r6 measured: register acc + DPP reduction plateaus at 66 us VALU-bound;
// this replaces 456 VALU/iter with ~20 (8 ds_add) and has NO reduction chain.
#define RSTRIDE 136                 // floats: 4 copies x 33 + 4 pad
#define WSTRIDE (2 * RSTRIDE)
__global__ __launch_bounds__(256) void k_sums(const float* __restrict__ fS,
                                              const float* __restrict__ fT,
                                              const int* __restrict__ labels,
                                              float* __restrict__ sumsS,
                                              float* __restrict__ sumsT) {
    __shared__ float acc[4 * WSTRIDE];   // 4352 B
    const int t = threadIdx.x;
    const int lane = t & 63;
    const int w = t >> 6;
    for (int i = t; i < 4 * WSTRIDE; i += 256) acc[i] = 0.f;
    __syncthreads();

    const int u = (blockIdx.x << 2) + w;    // b*512 + c, 0..4095
    const int b = u >> 9;
    const int c = u & 511;
    const float4* pS = (const float4*)(fS + (size_t)u * NHW);
    const float4* pT = (const float4*)(fT + (size_t)u * NHW);
    const int4* lab4 = (const int4*)(labels + b * NHW);

    float* aS = acc + w * WSTRIDE + (lane >> 4) * 33;
    float* aT = aS + RSTRIDE;

    #pragma unroll 4
    for (int i = 0; i < 16; ++i) {
        const int idx = lane + (i << 6);    // float4 index (4 pixels)
        const float4 vS = pS[idx];
        const float4 vT = pT[idx];
        const int4 l4 = lab4[idx];
        const unsigned lx = min((unsigned)l4.x, 19u);  // invalid -> dummy slot
        const unsigned ly = min((unsigned)l4.y, 19u);
        const unsigned lz = min((unsigned)l4.z, 19u);
        const unsigned lw = min((unsigned)l4.w, 19u);
        atomicAdd(&aS[lx], vS.x); atomicAdd(&aS[ly], vS.y);
        atomicAdd(&aS[lz], vS.z); atomicAdd(&aS[lw], vS.w);
        atomicAdd(&aT[lx], vT.x); atomicAdd(&aT[ly], vT.y);
        atomicAdd(&aT[lz], vT.z); atomicAdd(&aT[lw], vT.w);
    }
    __syncthreads();
    const float* base = acc + w * WSTRIDE;
    if (lane < NCLS) {
        float s = base[lane] + base[33 + lane] + base[66 + lane] + base[99 + lane];
        sumsS[((size_t)(b * NCLS + lane)) * NC + c] = s;
    } else if (lane >= 32 && lane < 32 + NCLS) {
        const int l = lane - 32;
        const float* bT = base + RSTRIDE;
        float s = bT[l] + bT[33 + l] + bT[66 + l] + bT[99 + l];
        sumsT[((size_t)(b * NCLS + l)) * NC + c] = s;
    }
}

// ---------------------------------------------------------------------------
// Kernel 3: means = sum/(count+eps) in place + per-(b,k) center norms.
// One wave per (b,k); sums layout [b][k][c] -> coalesced.
__global__ __launch_bounds__(64) void k_means(float* __restrict__ sumsS,
                                              float* __restrict__ sumsT,
                                              const float* __restrict__ counts,
                                              float* __restrict__ normS,
                                              float* __restrict__ normT) {
    const int bk = blockIdx.x;
    const int t = threadIdx.x;
    const float inv = 1.f / (counts[bk] + EPSM);
    const size_t row = (size_t)bk * NC;
    float aS = 0.f, aT = 0.f;
    #pragma unroll
    for (int i = 0; i < NC / 64; ++i) {
        const int c = t + i * 64;
        float mS = sumsS[row + c] * inv; sumsS[row + c] = mS; aS += mS * mS;
        float mT = sumsT[row + c] * inv; sumsT[row + c] = mT; aT += mT * mT;
    }
    aS = wave64_sum(aS);
    aT = wave64_sum(aT);
    if (t == 63) { normS[bk] = sqrtf(aS); normT[bk] = sqrtf(aT); }
}

// ---------------------------------------------------------------------------
// Kernel 4: per-pixel dot(f, mean[lab]) and ||f||^2, atomic-free.
// Each thread owns 2 adjacent pixels (float2 loads); 128-thread blocks.
// Grid: 8 b x 16 pixel-tiles(256 px) x 8 c-chunks = 1024 blocks.
// Means tile in LDS stride 65 -> gather bank = (lc+ci)%32, conflict-free.
#define CCH 64
__global__ __launch_bounds__(128) void k_dots(const float* __restrict__ fS,
                                              const float* __restrict__ fT,
                                              const float* __restrict__ meansS,
                                              const float* __restrict__ meansT,
                                              const int* __restrict__ labels,
                                              float* __restrict__ part) {
    __shared__ float mS[NCLS * 65];
    __shared__ float mT[NCLS * 65];
    const int blk = blockIdx.x;
    const int chunk = blk & 7;
    const int tile  = (blk >> 3) & 15;
    const int b     = blk >> 7;
    const int t = threadIdx.x;
    const int c0 = chunk * CCH;
    const int n0 = tile * 256 + t * 2;            // two adjacent pixels

    for (int i = t; i < NCLS * CCH; i += 128) {
        const int k = i >> 6, j = i & 63;
        mS[k * 65 + j] = meansS[((size_t)(b * NCLS + k)) * NC + c0 + j];
        mT[k * 65 + j] = meansT[((size_t)(b * NCLS + k)) * NC + c0 + j];
    }
    __syncthreads();

    const int2 l2 = *(const int2*)(labels + b * NHW + n0);
    const int lca = (l2.x >= 0 && l2.x < NCLS) ? l2.x : 0;
    const int lcb = (l2.y >= 0 && l2.y < NCLS) ? l2.y : 0;
    const float* pS = fS + ((size_t)(b * NC + c0)) * NHW + n0;
    const float* pT = fT + ((size_t)(b * NC + c0)) * NHW + n0;
    float dSa = 0.f, dSb = 0.f, nSa = 0.f, nSb = 0.f;
    float dTa = 0.f, dTb = 0.f, nTa = 0.f, nTb = 0.f;
    #pragma unroll 16
    for (int ci = 0; ci < CCH; ++ci) {
        const float2 vS = *(const float2*)(pS + (size_t)ci * NHW);
        const float2 vT = *(const float2*)(pT + (size_t)ci * NHW);
        const float msa = mS[lca * 65 + ci];
        const float msb = mS[lcb * 65 + ci];
        const float mta = mT[lca * 65 + ci];
        const float mtb = mT[lcb * 65 + ci];
        dSa += vS.x * msa; nSa += vS.x * vS.x;
        dSb += vS.y * msb; nSb += vS.y * vS.y;
        dTa += vT.x * mta; nTa += vT.x * vT.x;
        dTb += vT.y * mtb; nTb += vT.y * vT.y;
    }
    const size_t p0 = (size_t)b * NHW + n0;
    *(float2*)(part + ((size_t)(0 * 8 + chunk)) * (NB * NHW) + p0) = make_float2(dSa, dSb);
    *(float2*)(part + ((size_t)(1 * 8 + chunk)) * (NB * NHW) + p0) = make_float2(nSa, nSb);
    *(float2*)(part + ((size_t)(2 * 8 + chunk)) * (NB * NHW) + p0) = make_float2(dTa, dTb);
    *(float2*)(part + ((size_t)(3 * 8 + chunk)) * (NB * NHW) + p0) = make_float2(nTa, nTb);
}

// ---------------------------------------------------------------------------
// Kernel 5: combine partials, cosines, MSE reduce.
__global__ __launch_bounds__(256) void k_final(const float* __restrict__ part,
                                               const int* __restrict__ labels,
                                               const float* __restrict__ normS,
                                               const float* __restrict__ normT,
                                               float* __restrict__ out) {
    __shared__ float red[4];
    const int p = blockIdx.x * 256 + threadIdx.x;
    const int b = p >> 12;
    float dS = 0.f, nS = 0.f, dT = 0.f, nT = 0.f;
    #pragma unroll
    for (int ch = 0; ch < 8; ++ch) {
        dS += part[((size_t)(0 * 8 + ch)) * (NB * NHW) + p];
        nS += part[((size_t)(1 * 8 + ch)) * (NB * NHW) + p];
        dT += part[((size_t)(2 * 8 + ch)) * (NB * NHW) + p];
        nT += part[((size_t)(3 * 8 + ch)) * (NB * NHW) + p];
    }
    const int l = labels[p];
    float val = 0.f;
    if (l >= 0 && l < NCLS) {
        float cS = dS / (fmaxf(sqrtf(nS), EPSC) * fmaxf(normS[b * NCLS + l], EPSC));
        float cT = dT / (fmaxf(sqrtf(nT), EPSC) * fmaxf(normT[b * NCLS + l], EPSC));
        float d = cS - cT;
        val = d * d;
    }
    val = wave64_sum(val);
    if ((threadIdx.x & 63) == 63) red[threadIdx.x >> 6] = val;
    __syncthreads();
    if (threadIdx.x == 0)
        atomicAdd(out, (red[0] + red[1] + red[2] + red[3]) * (1.f / (NB * NHW)));
}

// ---------------------------------------------------------------------------
extern "C" void kernel_launch(void* const* d_in, const int* in_sizes, int n_in,
                              void* d_out, int out_size, void* d_ws, size_t ws_size,
                              hipStream_t stream) {
    (void)in_sizes; (void)n_in; (void)out_size; (void)ws_size;
    const float* fS     = (const float*)d_in[0];
    const float* fT     = (const float*)d_in[1];
    const int*   target = (const int*)d_in[2];

    char* ws = (char*)d_ws;
    int*   labels = (int*)  (ws + OFF_LABELS);
    float* counts = (float*)(ws + OFF_COUNTS);
    float* sumsS  = (float*)(ws + OFF_SUMS_S);   // becomes meansS in place
    float* sumsT  = (float*)(ws + OFF_SUMS_T);   // becomes meansT in place
    float* normS  = (float*)(ws + OFF_NORM_S);
    float* normT  = (float*)(ws + OFF_NORM_T);
    float* part   = (float*)(ws + OFF_PART);

    k_labels<<<NB, 256, 0, stream>>>(target, labels, counts, (float*)d_out);
    k_sums  <<<NB * NC / 4, 256, 0, stream>>>(fS, fT, labels, sumsS, sumsT);
    k_means <<<NB * NCLS, 64, 0, stream>>>(sumsS, sumsT, counts, normS, normT);
    k_dots  <<<NB * 16 * 8, 128, 0, stream>>>(fS, fT, sumsS, sumsT, labels, part);
    k_final <<<NB * NHW / 256, 256, 0, stream>>>(part, labels, normS, normT,
                                                 (float*)d_out);
}